// Round 18
// baseline (192.063 us; speedup 1.0000x reference)
//
#include <hip/hip_runtime.h>
#include <hip/hip_bf16.h>

// SingleAttention: q/k/v = X@W+b (fp32 in), out = softmax(q k^T/16) v, fp32 out.
// B=8 S=2048 D_IN=512 D_K=D_V=256.
// ws: EXACTLY 16 MB:
//   ks = 8 MB: [b][128 tiles][8KB K-tile image, fragment-major]
//        element (kv<16, dim<256) at byte d*1024 + (g*16+kv)*16 + j*2
//        where d=dim>>5, g=(dim>>3)&3, j=dim&7   (QK^T b128-read order)
//   vt = 8 MB: [b][128 tiles][8KB V-tile image, fragment-major]
//        element (kv<16, dv<256) at byte f*512 + (gv*16+cc)*8 + (kv&3)*2
//        where f=dv>>4, cc=dv&15, gv=kv>>2       (PV b64-read order)
// Q (bf16, scaled 0.0625*log2e) stashed in first 512B of each d_out row.
//
// Measured laws driving this design (R8-R16): VGPR cap = 65536/block_threads
// (256thr -> 220+ proven); block-wide barriers drain DMA (~20% stall);
// LDS read traffic dominates attn. Hence: 256-thr blocks, 32q/wave,
// wave-private staging with counted vmcnt, KVBLK=16 so the S^T fragment IS
// the PV A-operand (P never touches LDS), zero barriers in the kv loop.

typedef __attribute__((ext_vector_type(4))) float f32x4;
typedef __attribute__((ext_vector_type(8))) short s16x8;
typedef __attribute__((ext_vector_type(4))) short s16x4;
typedef __attribute__((ext_vector_type(2))) unsigned int u32x2;
typedef unsigned int u32;

static __device__ __forceinline__ short f2bf(float x) {
  __hip_bfloat16 h = __float2bfloat16(x);
  return *reinterpret_cast<short*>(&h);
}
static __device__ __forceinline__ u32 pack2bf(float lo, float hi) {
  return (u32)(unsigned short)f2bf(lo) | ((u32)(unsigned short)f2bf(hi) << 16);
}
static __device__ __forceinline__ float ex2(float x) {
  return __builtin_amdgcn_exp2f(x);
}
static __device__ __forceinline__ void gload16(const void* g, void* l) {
  __builtin_amdgcn_global_load_lds(
      (const __attribute__((address_space(1))) u32*)g,
      (__attribute__((address_space(3))) u32*)l, 16, 0, 0);
}
// D = A(16x16 P-frag, 4 bf16/lane) * B(16x16 V-frag, 4 bf16/lane) + C.
// Host pass must not see amdgcn builtins (R17 compile failure).
static __device__ __forceinline__ f32x4 mfma16(s16x4 a, s16x4 b, f32x4 c) {
#if defined(__HIP_DEVICE_COMPILE__)
#if __has_builtin(__builtin_amdgcn_mfma_f32_16x16x16bf16_1k)
  return __builtin_amdgcn_mfma_f32_16x16x16bf16_1k(a, b, c, 0, 0, 0);
#else
  f32x4 d;
  asm volatile(
      "s_nop 1\n\t"
      "v_mfma_f32_16x16x16_bf16 %0, %1, %2, %3\n\t"
      "s_nop 7\n\t"
      "s_nop 7"
      : "=v"(d)
      : "v"(a), "v"(b), "v"(c));
  return d;
#endif
#else
  (void)a;
  (void)b;
  return c;
#endif
}

// Projection: P[16384,256] = X @ W + b -> bf16. Tile 64 rows x 256 cols so X
// is fetched from HBM exactly once. Grid 768 = 256 m-tiles x 3 z.
// z=0 -> qs (exp2-scaled, row stride 512); z=1 -> K images; z=2 -> V images.
__global__ __launch_bounds__(256) void proj3(
    const float* __restrict__ q_in, const float* __restrict__ k_in,
    const float* __restrict__ v_in, const float* __restrict__ bq,
    const float* __restrict__ bk, const float* __restrict__ bv,
    const float* __restrict__ Wq, const float* __restrict__ Wk,
    const float* __restrict__ Wv, short* __restrict__ qs,
    char* __restrict__ ks, char* __restrict__ vt) {
  const int bid = blockIdx.x;
  const int z = bid % 3;
  const int m0 = (bid / 3) * 64;
  const float* X = z == 0 ? q_in : z == 1 ? k_in : v_in;
  const float* W = z == 0 ? Wq : z == 1 ? Wk : Wv;
  const float* bias = z == 0 ? bq : z == 1 ? bk : bv;
  const float sc = z == 0 ? 0.09016844f : 1.0f;  // 0.0625*log2(e) for z=0

  __shared__ short As[64][40];
  __shared__ short Bs[256][40];

  const int tid = threadIdx.x;
  const int lane = tid & 63;
  const int wid = tid >> 6;
  const int wr = wid >> 1, wc = wid & 1;  // wave tile: rows wr*32, cols wc*128
  const int g = lane >> 4, c = lane & 15;

  f32x4 acc[2][8];
#pragma unroll
  for (int m = 0; m < 2; m++)
#pragma unroll
    for (int n = 0; n < 8; n++) acc[m][n] = (f32x4)0.0f;

  const int arow = tid >> 2, aseg = tid & 3;  // A: 64 rows x 32 fp32
  const int bn = tid;                         // B: 256 cols x 32 k

  for (int kt = 0; kt < 16; ++kt) {
    const int k0 = kt * 32;
    const float* ap = &X[(m0 + arow) * 512 + k0 + aseg * 8];
    f32x4 a0 = *(const f32x4*)(ap + 0);
    f32x4 a1 = *(const f32x4*)(ap + 4);
    float wv[32];
#pragma unroll
    for (int j = 0; j < 32; j++) wv[j] = W[(k0 + j) * 256 + bn] * sc;
    __syncthreads();  // prev frag reads done
    s16x8 ac;
#pragma unroll
    for (int i = 0; i < 4; i++) {
      ac[i] = f2bf(a0[i]);
      ac[i + 4] = f2bf(a1[i]);
    }
    *(s16x8*)&As[arow][aseg * 8] = ac;
#pragma unroll
    for (int s = 0; s < 4; s++) {
      s16x8 w8;
#pragma unroll
      for (int j = 0; j < 8; j++) w8[j] = f2bf(wv[s * 8 + j]);
      *(s16x8*)&Bs[bn][s * 8] = w8;
    }
    __syncthreads();
    s16x8 af[2], bfr[8];
#pragma unroll
    for (int m = 0; m < 2; m++)
      af[m] = *(const s16x8*)&As[wr * 32 + m * 16 + c][g * 8];
#pragma unroll
    for (int n = 0; n < 8; n++)
      bfr[n] = *(const s16x8*)&Bs[wc * 128 + n * 16 + c][g * 8];
#pragma unroll
    for (int m = 0; m < 2; m++)
#pragma unroll
      for (int n = 0; n < 8; n++)
        acc[m][n] = __builtin_amdgcn_mfma_f32_16x16x32_bf16(af[m], bfr[n],
                                                            acc[m][n], 0, 0, 0);
  }

  float bv8[8];
#pragma unroll
  for (int n = 0; n < 8; n++) bv8[n] = bias[wc * 128 + n * 16 + c] * sc;

  if (z == 0) {
#pragma unroll
    for (int m = 0; m < 2; m++) {
      const int row0 = m0 + wr * 32 + m * 16 + g * 4;
#pragma unroll
      for (int n = 0; n < 8; n++) {
        const int col = wc * 128 + n * 16 + c;
#pragma unroll
        for (int r = 0; r < 4; r++)
          qs[(row0 + r) * 512 + col] = f2bf(acc[m][n][r] + bv8[n]);
      }
    }
  } else if (z == 1) {
    // K fragment-major image
#pragma unroll
    for (int m = 0; m < 2; m++) {
      const int row0 = m0 + wr * 32 + m * 16 + g * 4;
#pragma unroll
      for (int n = 0; n < 8; n++) {
        const int col = wc * 128 + n * 16 + c;  // dim
        const int d = col >> 5, gg = (col >> 3) & 3, j = col & 7;
#pragma unroll
        for (int r = 0; r < 4; r++) {
          const int rowg = row0 + r;
          const int bb = rowg >> 11, s = rowg & 2047;
          const int tile = s >> 4, kvl = s & 15;
          const u32 off = (u32)(d * 1024 + (gg * 16 + kvl) * 16 + j * 2);
          *(short*)(ks + ((size_t)(bb * 128 + tile) << 13) + off) =
              f2bf(acc[m][n][r] + bv8[n]);
        }
      }
    }
  } else {
    // V fragment-major image (4 consecutive kv per 8B chunk)
#pragma unroll
    for (int m = 0; m < 2; m++) {
      const int row0 = m0 + wr * 32 + m * 16 + g * 4;  // kv row, mult of 4
      const int bb = row0 >> 11, s = row0 & 2047;
      const int tile = s >> 4, kvl = s & 15;
      const int gv = kvl >> 2;
#pragma unroll
      for (int n = 0; n < 8; n++) {
        const int dv = wc * 128 + n * 16 + c;
        const int f = dv >> 4, cc = dv & 15;
        s16x4 pk;
#pragma unroll
        for (int r = 0; r < 4; r++) pk[r] = f2bf(acc[m][n][r] + bv8[n]);
        const u32 off = (u32)(f * 512 + (gv * 16 + cc) * 8);
        *(s16x4*)(vt + ((size_t)(bb * 128 + tile) << 13) + off) = pk;
      }
    }
  }
}

// Flash attention, barrier-free kv loop. Grid 512: b = bid&7 (XCD-local),
// q0 = (bid>>3)*32. 256 threads = 4 waves; each wave = one kv quarter
// (512 kv = 32 tiles of KVBLK=16), 32 q-rows (qsub 0/1), wave-private
// K/V staging (8KB each) via global_load_lds + counted vmcnt. S^T fragment
// from swapped QK^T is directly the PV A-operand (mfma 16x16x16) -> P stays
// in registers. 4-way merge in LDS at the end.
__global__ __launch_bounds__(256) void attn_fused(
    const short* __restrict__ qs, const char* __restrict__ ksb,
    const char* __restrict__ vtb, float* __restrict__ out) {
  const int bid = blockIdx.x;
  const int b = bid & 7;
  const int q0 = (bid >> 3) * 32;

  // LDS (66560 B -> 2 blocks/CU):
  //   wid*16384: K 8KB @0, V 8KB @8192          (65536 B)
  //   65536: Ml [4][32][2] f32                  (1024 B)
  //   merge overlay: Om [32][260] f32 @0 (33280 B, stage dead by then)
  __shared__ __align__(16) char smem[66560];

  const int tid = threadIdx.x;
  const int lane = tid & 63;
  const int grp = tid >> 6;  // 0..3 kv quarter
  const int g = lane >> 4, c = lane & 15;

  char* Kb = smem + grp * 16384;
  char* Vb = Kb + 8192;
  float* Mlf = (float*)(smem + 65536);  // [4][32][2]

  // hoist Q fragments (bf16, exp2 units): 32 q-rows
  s16x8 qf[2][8];
#pragma unroll
  for (int qsub = 0; qsub < 2; qsub++) {
    const int qrow = (b << 11) + q0 + qsub * 16 + c;
#pragma unroll
    for (int d = 0; d < 8; d++)
      qf[qsub][d] = *(const s16x8*)&qs[qrow * 512 + d * 32 + g * 8];
  }
  __builtin_amdgcn_sched_barrier(0);
  asm volatile("s_waitcnt vmcnt(0)" ::: "memory");  // Q loads out of vmcnt
  __builtin_amdgcn_sched_barrier(0);

  f32x4 o[2][16];
#pragma unroll
  for (int qsub = 0; qsub < 2; qsub++)
#pragma unroll
    for (int f = 0; f < 16; f++) o[qsub][f] = (f32x4)0.0f;
  float m_l[2] = {-1e30f, -1e30f};
  float l_l[2] = {0.f, 0.f};

  const char* kim = ksb + ((size_t)(b * 128 + grp * 32) << 13) + lane * 16;
  const char* vim = vtb + ((size_t)(b * 128 + grp * 32) << 13) + lane * 16;

  // prologue: stage tile 0 (8 K-loads then 8 V-loads; order matters for vmcnt)
#pragma unroll
  for (int i = 0; i < 8; i++) gload16(kim + i * 1024, Kb + i * 1024);
#pragma unroll
  for (int i = 0; i < 8; i++) gload16(vim + i * 1024, Vb + i * 1024);

  for (int t = 0; t < 32; ++t) {
    // wait K(t): 16 outstanding -> 8 leaves only the V group in flight
    __builtin_amdgcn_sched_barrier(0);
    asm volatile("s_waitcnt vmcnt(8)" ::: "memory");
    __builtin_amdgcn_sched_barrier(0);

    // S^T = K Q^T: sf[qsub][r] = S[q=c][kv = g*4 + r]
    f32x4 sf[2];
    sf[0] = (f32x4)0.0f;
    sf[1] = (f32x4)0.0f;
    __builtin_amdgcn_s_setprio(1);
#pragma unroll
    for (int d = 0; d < 8; ++d) {
      const s16x8 kf = *(const s16x8*)(Kb + d * 1024 + lane * 16);
      sf[0] = __builtin_amdgcn_mfma_f32_16x16x32_bf16(kf, qf[0][d], sf[0], 0, 0, 0);
      sf[1] = __builtin_amdgcn_mfma_f32_16x16x32_bf16(kf, qf[1][d], sf[1], 0, 0, 0);
    }
    __builtin_amdgcn_s_setprio(0);

    // K LDS reads drained -> prefetch K(t+1) into the same buffer
    __builtin_amdgcn_sched_barrier(0);
    asm volatile("s_waitcnt lgkmcnt(0)" ::: "memory");
    __builtin_amdgcn_sched_barrier(0);
    if (t < 31) {
      const char* ksrc = kim + (size_t)(t + 1) * 8192;
#pragma unroll
      for (int i = 0; i < 8; i++) gload16(ksrc + i * 1024, Kb + i * 1024);
    }

    // lane-local online softmax (exp2 units, defer-max THR=11)
    float mx[2];
#pragma unroll
    for (int qsub = 0; qsub < 2; qsub++) {
      float m0 = fmaxf(fmaxf(sf[qsub][0], sf[qsub][1]),
                       fmaxf(sf[qsub][2], sf[qsub][3]));
      m0 = fmaxf(m0, __shfl_xor(m0, 16, 64));
      m0 = fmaxf(m0, __shfl_xor(m0, 32, 64));
      mx[qsub] = m0;
    }
    if (__any((mx[0] > m_l[0] + 11.f) | (mx[1] > m_l[1] + 11.f))) {
#pragma unroll
      for (int qsub = 0; qsub < 2; qsub++) {
        const float mn = fmaxf(m_l[qsub], mx[qsub]);
        const float scr = ex2(m_l[qsub] - mn);
        m_l[qsub] = mn;
        l_l[qsub] *= scr;
        float so[4];
#pragma unroll
        for (int r = 0; r < 4; r++) so[r] = __shfl(scr, g * 4 + r, 64);
#pragma unroll
        for (int f = 0; f < 16; f++)
#pragma unroll
          for (int r = 0; r < 4; r++) o[qsub][f][r] *= so[r];
      }
    }
    s16x4 pa[2];
#pragma unroll
    for (int qsub = 0; qsub < 2; qsub++) {
      float sum = 0.f;
#pragma unroll
      for (int r = 0; r < 4; r++) {
        const float p = ex2(sf[qsub][r] - m_l[qsub]);
        sf[qsub][r] = p;
        sum += p;
      }
      sum += __shfl_xor(sum, 16, 64);
      sum += __shfl_xor(sum, 32, 64);
      l_l[qsub] += sum;
      u32x2 tv;
      tv[0] = pack2bf(sf[qsub][0], sf[qsub][1]);
      tv[1] = pack2bf(sf[qsub][2], sf[qsub][3]);
      pa[qsub] = *(s16x4*)&tv;  // PV A-operand: row=q=c, k=kv=g*4+j
    }

    // wait V(t): ≤8 V(t) + 8 K(t+1) outstanding (t<31); last iter drain all
    __builtin_amdgcn_sched_barrier(0);
    if (t < 31) {
      asm volatile("s_waitcnt vmcnt(8)" ::: "memory");
    } else {
      asm volatile("s_waitcnt vmcnt(0)" ::: "memory");
    }
    __builtin_amdgcn_sched_barrier(0);

    // O += P V  (16x16x16: B=V fragment, col=dv, k=kv)
    __builtin_amdgcn_s_setprio(1);
#pragma unroll
    for (int f = 0; f < 16; ++f) {
      const s16x4 vf = *(const s16x4*)(Vb + f * 512 + lane * 8);
      o[0][f] = mfma16(pa[0], vf, o[0][f]);
      o[1][f] = mfma16(pa[1], vf, o[1][f]);
    }
    __builtin_amdgcn_s_setprio(0);

    // V LDS reads drained -> prefetch V(t+1)
    __builtin_amdgcn_sched_barrier(0);
    asm volatile("s_waitcnt lgkmcnt(0)" ::: "memory");
    __builtin_amdgcn_sched_barrier(0);
    if (t < 31) {
      const char* vsrc = vim + (size_t)(t + 1) * 8192;
#pragma unroll
      for (int i = 0; i < 8; i++) gload16(vsrc + i * 1024, Vb + i * 1024);
    }
  }

  // ---- 4-way merge of kv-quarter states ----
  __syncthreads();
  if (g == 0) {
#pragma unroll
    for (int qsub = 0; qsub < 2; qsub++) {
      Mlf[(grp * 32 + qsub * 16 + c) * 2 + 0] = m_l[qsub];
      Mlf[(grp * 32 + qsub * 16 + c) * 2 + 1] = l_l[qsub];
    }
  }
  __syncthreads();
  float eown[2][4], inv4[2][4];
#pragma unroll
  for (int qsub = 0; qsub < 2; qsub++)
#pragma unroll
    for (int r = 0; r < 4; r++) {
      const int rw = qsub * 16 + g * 4 + r;
      float ms = -1e30f;
#pragma unroll
      for (int gg = 0; gg < 4; gg++) ms = fmaxf(ms, Mlf[(gg * 32 + rw) * 2]);
      float den = 0.f;
#pragma unroll
      for (int gg = 0; gg < 4; gg++)
        den += ex2(Mlf[(gg * 32 + rw) * 2] - ms) * Mlf[(gg * 32 + rw) * 2 + 1];
      eown[qsub][r] = ex2(Mlf[(grp * 32 + rw) * 2] - ms);
      inv4[qsub][r] = 1.0f / den;
    }
  float* Omf = (float*)smem;  // [32][260] overlay on stage region
  for (int gg = 0; gg < 4; ++gg) {
    if (grp == gg) {
#pragma unroll
      for (int qsub = 0; qsub < 2; qsub++)
#pragma unroll
        for (int f = 0; f < 16; f++)
#pragma unroll
          for (int r = 0; r < 4; r++) {
            const int rw = qsub * 16 + g * 4 + r;
            const int idx = rw * 260 + f * 16 + c;
            const float v = eown[qsub][r] * o[qsub][f][r];
            if (gg == 0)
              Omf[idx] = v;
            else
              Omf[idx] += v;
          }
    }
    __syncthreads();
  }
  if (grp == 0) {
#pragma unroll
    for (int qsub = 0; qsub < 2; qsub++)
#pragma unroll
      for (int f = 0; f < 16; f++)
#pragma unroll
        for (int r = 0; r < 4; r++) {
          const int rw = qsub * 16 + g * 4 + r;
          out[((b << 11) + q0 + rw) * 256 + f * 16 + c] =
              Omf[rw * 260 + f * 16 + c] * inv4[qsub][r];
        }
  }
}

extern "C" void kernel_launch(void* const* d_in, const int* in_sizes, int n_in,
                              void* d_out, int out_size, void* d_ws,
                              size_t ws_size, hipStream_t stream) {
  const float* q_in = (const float*)d_in[0];
  const float* k_in = (const float*)d_in[1];
  const float* v_in = (const float*)d_in[2];
  const float* Wq = (const float*)d_in[3];
  const float* bq = (const float*)d_in[4];
  const float* Wk = (const float*)d_in[5];
  const float* bk = (const float*)d_in[6];
  const float* Wv = (const float*)d_in[7];
  const float* bv = (const float*)d_in[8];
  float* out = (float*)d_out;

  char* ws = (char*)d_ws;
  short* qsb = (short*)d_out;  // Q bf16 in first 512B of each out row
  char* ksb = ws;              // 8 MB K fragment-major tile images
  char* vtb = ws + (8 << 20);  // 8 MB V fragment-major tile images

  proj3<<<dim3(768), dim3(256), 0, stream>>>(q_in, k_in, v_in, bq, bk, bv, Wq,
                                             Wk, Wv, qsb, ksb, vtb);
  attn_fused<<<dim3(512), dim3(256), 0, stream>>>(qsb, ksb, vtb, out);
}

// Round 19
// 107.946 us; speedup vs baseline: 1.7792x; 1.7792x over previous
//
#include <hip/hip_runtime.h>
#include <hip/hip_bf16.h>

// SingleAttention: q/k/v = X@W+b (fp32 in), out = softmax(q k^T/16) v, fp32 out.
// B=8 S=2048 D_IN=512 D_K=D_V=256.
// ws: EXACTLY 16 MB:
//   ks = 8 MB: [b][64 tiles][16KB K-tile image, fragment-major for the
//        swapped-QK^T A-operand]: element (kv<32, dim<256) at byte
//        nf*8192 + d*1024 + (g*16 + cc)*16 + j*2
//        with nf=kv>>4, cc=kv&15, d=dim>>5, g=(dim>>3)&3, j=dim&7.
//        QK^T read: Kb + nf*8192 + d*1024 + lane*16  (sequential, 0-conflict)
//   vt = 8 MB: [b][64 tiles][16KB V-tile image, fragment-major for the PV
//        B-operand]: element (kv<32, dv<256) at byte
//        f*1024 + (gv*16 + cc)*16 + j*2
//        with gv=kv>>3, j=kv&7, f=dv>>4, cc=dv&15.
//        PV read: Vb + f*1024 + lane*16  (sequential, 0-conflict)
// Q (bf16, scaled 0.0625*log2e -> exp2-unit softmax) stashed in first 512B of
// each d_out row; each attn block reads only its own rows then overwrites.
//
// Measured: R16 champion structure (68.5us attn) carried 9.2M LDS bank-
// conflict cycles (~15us serialized); R18 proved fragment-major images give
// ZERO conflicts. This round = R16 structure + R18 images, nothing else.

typedef __attribute__((ext_vector_type(4))) float f32x4;
typedef __attribute__((ext_vector_type(8))) short s16x8;
typedef __attribute__((ext_vector_type(4))) short s16x4;
typedef unsigned int u32;
typedef unsigned long long u64;

static __device__ __forceinline__ short f2bf(float x) {
  __hip_bfloat16 h = __float2bfloat16(x);
  return *reinterpret_cast<short*>(&h);
}
static __device__ __forceinline__ u32 pack2bf(float lo, float hi) {
  return (u32)(unsigned short)f2bf(lo) | ((u32)(unsigned short)f2bf(hi) << 16);
}
static __device__ __forceinline__ float ex2(float x) {
  return __builtin_amdgcn_exp2f(x);
}
static __device__ __forceinline__ void gload16(const void* g, void* l) {
  __builtin_amdgcn_global_load_lds(
      (const __attribute__((address_space(1))) u32*)g,
      (__attribute__((address_space(3))) u32*)l, 16, 0, 0);
}

// Projection: P[16384,256] = X @ W + b -> bf16. Tile 64 rows x 256 cols so X
// is fetched from HBM exactly once. Grid 768 = 256 m-tiles x 3 z.
// z=0 -> qs (exp2-scaled, row stride 512); z=1 -> K images; z=2 -> V images.
__global__ __launch_bounds__(256) void proj3(
    const float* __restrict__ q_in, const float* __restrict__ k_in,
    const float* __restrict__ v_in, const float* __restrict__ bq,
    const float* __restrict__ bk, const float* __restrict__ bv,
    const float* __restrict__ Wq, const float* __restrict__ Wk,
    const float* __restrict__ Wv, short* __restrict__ qs,
    char* __restrict__ ks, char* __restrict__ vt) {
  const int bid = blockIdx.x;
  const int z = bid % 3;
  const int m0 = (bid / 3) * 64;
  const float* X = z == 0 ? q_in : z == 1 ? k_in : v_in;
  const float* W = z == 0 ? Wq : z == 1 ? Wk : Wv;
  const float* bias = z == 0 ? bq : z == 1 ? bk : bv;
  const float sc = z == 0 ? 0.09016844f : 1.0f;  // 0.0625*log2(e) for z=0

  __shared__ short As[64][40];
  __shared__ short Bs[256][40];

  const int tid = threadIdx.x;
  const int lane = tid & 63;
  const int wid = tid >> 6;
  const int wr = wid >> 1, wc = wid & 1;  // wave tile: rows wr*32, cols wc*128
  const int g = lane >> 4, c = lane & 15;

  f32x4 acc[2][8];
#pragma unroll
  for (int m = 0; m < 2; m++)
#pragma unroll
    for (int n = 0; n < 8; n++) acc[m][n] = (f32x4)0.0f;

  const int arow = tid >> 2, aseg = tid & 3;  // A: 64 rows x 32 fp32
  const int bn = tid;                         // B: 256 cols x 32 k

  for (int kt = 0; kt < 16; ++kt) {
    const int k0 = kt * 32;
    const float* ap = &X[(m0 + arow) * 512 + k0 + aseg * 8];
    f32x4 a0 = *(const f32x4*)(ap + 0);
    f32x4 a1 = *(const f32x4*)(ap + 4);
    float wv[32];
#pragma unroll
    for (int j = 0; j < 32; j++) wv[j] = W[(k0 + j) * 256 + bn] * sc;
    __syncthreads();  // prev frag reads done
    s16x8 ac;
#pragma unroll
    for (int i = 0; i < 4; i++) {
      ac[i] = f2bf(a0[i]);
      ac[i + 4] = f2bf(a1[i]);
    }
    *(s16x8*)&As[arow][aseg * 8] = ac;
#pragma unroll
    for (int s = 0; s < 4; s++) {
      s16x8 w8;
#pragma unroll
      for (int j = 0; j < 8; j++) w8[j] = f2bf(wv[s * 8 + j]);
      *(s16x8*)&Bs[bn][s * 8] = w8;
    }
    __syncthreads();
    s16x8 af[2], bfr[8];
#pragma unroll
    for (int m = 0; m < 2; m++)
      af[m] = *(const s16x8*)&As[wr * 32 + m * 16 + c][g * 8];
#pragma unroll
    for (int n = 0; n < 8; n++)
      bfr[n] = *(const s16x8*)&Bs[wc * 128 + n * 16 + c][g * 8];
#pragma unroll
    for (int m = 0; m < 2; m++)
#pragma unroll
      for (int n = 0; n < 8; n++)
        acc[m][n] = __builtin_amdgcn_mfma_f32_16x16x32_bf16(af[m], bfr[n],
                                                            acc[m][n], 0, 0, 0);
  }

  float bv8[8];
#pragma unroll
  for (int n = 0; n < 8; n++) bv8[n] = bias[wc * 128 + n * 16 + c] * sc;

  if (z == 0) {
#pragma unroll
    for (int m = 0; m < 2; m++) {
      const int row0 = m0 + wr * 32 + m * 16 + g * 4;
#pragma unroll
      for (int n = 0; n < 8; n++) {
        const int col = wc * 128 + n * 16 + c;
#pragma unroll
        for (int r = 0; r < 4; r++)
          qs[(row0 + r) * 512 + col] = f2bf(acc[m][n][r] + bv8[n]);
      }
    }
  } else if (z == 1) {
    // K fragment-major image (16KB per 32-kv tile)
#pragma unroll
    for (int m = 0; m < 2; m++) {
      const int row0 = m0 + wr * 32 + m * 16 + g * 4;
#pragma unroll
      for (int n = 0; n < 8; n++) {
        const int col = wc * 128 + n * 16 + c;  // dim
        const int d = col >> 5, gg = (col >> 3) & 3, j = col & 7;
#pragma unroll
        for (int r = 0; r < 4; r++) {
          const int rowg = row0 + r;
          const int bb = rowg >> 11, s = rowg & 2047;
          const int tile = s >> 5, kvl = s & 31;
          const int nf = kvl >> 4, cc = kvl & 15;
          const u32 off =
              (u32)(nf * 8192 + d * 1024 + (gg * 16 + cc) * 16 + j * 2);
          *(short*)(ks + ((size_t)(bb * 64 + tile) << 14) + off) =
              f2bf(acc[m][n][r] + bv8[n]);
        }
      }
    }
  } else {
    // V fragment-major image (16KB per 32-kv tile); 4 consecutive kv -> s16x4
#pragma unroll
    for (int m = 0; m < 2; m++) {
      const int row0 = m0 + wr * 32 + m * 16 + g * 4;  // kv row, mult of 4
      const int bb = row0 >> 11, s = row0 & 2047;
      const int tile = s >> 5, kvl = s & 31;
      const int gv = kvl >> 3, j0 = kvl & 7;  // j0 in {0,4}
#pragma unroll
      for (int n = 0; n < 8; n++) {
        const int dv = wc * 128 + n * 16 + c;
        const int f = dv >> 4, cc = dv & 15;
        s16x4 pk;
#pragma unroll
        for (int r = 0; r < 4; r++) pk[r] = f2bf(acc[m][n][r] + bv8[n]);
        const u32 off = (u32)(f * 1024 + (gv * 16 + cc) * 16 + j0 * 2);
        *(s16x4*)(vt + ((size_t)(bb * 64 + tile) << 14) + off) = pk;
      }
    }
  }
}

// Flash attention (R16 champion structure + fragment-major images).
// Flat grid 256: b = bid&7 (XCD-local batch), q0=(bid>>3)*64. 512 threads =
// 8 waves: grp = wid>>2 (kv half, 32 tiles of KVBLK=32), wq = wid&3 (16
// q-rows). Per-group double-buffered global_load_lds staging; sequential
// zero-conflict LDS reads; swapped QK^T lane-local softmax (exp2 units);
// defer-max; ONE barrier per iteration.
__global__ __launch_bounds__(512, 1) void attn_fused(
    const short* __restrict__ qs, const char* __restrict__ ksb,
    const char* __restrict__ vtb, float* __restrict__ out) {
  const int bid = blockIdx.x;
  const int b = bid & 7;
  const int q0 = (bid >> 3) * 64;

  // LDS carve (141312 B):
  //   stage: grp*65536 + sel*32768 + {0: K 16KB, 16384: V 16KB}   (131072 B)
  //   Ps:    131072 + wid*1280, [16 q][40 shorts]                 (10240 B)
  //   merge overlay: Om [64][260] f32 at 0; Ml [64][2] f32 at 66560
  __shared__ __align__(16) char smem[141312];

  const int tid = threadIdx.x;
  const int lane = tid & 63;
  const int wid = tid >> 6;
  const int grp = wid >> 2;    // kv half
  const int wq = wid & 3;      // q quarter (16 rows)
  const int gtid = tid & 255;  // within group
  const int g = lane >> 4, c = lane & 15;

  const char* ktiles = ksb + ((size_t)b << 20);  // 64 tiles * 16KB = 1MB
  const char* vtiles = vtb + ((size_t)b << 20);

  char* gbase = smem + grp * 65536;
  short* Ps = (short*)(smem + 131072 + wid * 1280);  // [16][40]

  // hoist Q fragments (bf16, exp2 units)
  s16x8 qf[8];
  {
    const int qrow = (b << 11) + q0 + wq * 16 + c;
#pragma unroll
    for (int d = 0; d < 8; d++)
      qf[d] = *(const s16x8*)&qs[qrow * 512 + d * 32 + g * 8];
  }

  f32x4 o[16];
#pragma unroll
  for (int f = 0; f < 16; f++) o[f] = (f32x4)0.0f;
  float m_l = -1e30f;  // running max (log2 units) of q-row c
  float l_l = 0.f;

  auto STAGE = [&](int t, int sel) {
    const size_t toff = (size_t)(grp * 32 + t) << 14;
    char* kd = gbase + sel * 32768;
    char* vd = kd + 16384;
    const char* ksrc = ktiles + toff + gtid * 16;
    const char* vsrc = vtiles + toff + gtid * 16;
#pragma unroll
    for (int i = 0; i < 4; i++) {
      gload16(ksrc + i * 4096, kd + gtid * 16 + i * 4096);
      gload16(vsrc + i * 4096, vd + gtid * 16 + i * 4096);
    }
  };

  STAGE(0, 0);
  __syncthreads();  // drain prologue stage

  for (int t = 0; t < 32; ++t) {
    const int sel = t & 1;
    if (t < 31) STAGE(t + 1, sel ^ 1);  // flies under this tile's compute

    const char* Kb = gbase + sel * 32768;
    const char* Vb = Kb + 16384;

    // S^T = K Q^T (swapped): sf[nf][r] = S[q=c][kv = nf*16 + g*4 + r]
    f32x4 sf[2];
    sf[0] = (f32x4)0.0f;
    sf[1] = (f32x4)0.0f;
    __builtin_amdgcn_s_setprio(1);
#pragma unroll
    for (int d = 0; d < 8; ++d) {
      const s16x8 kf0 = *(const s16x8*)(Kb + d * 1024 + lane * 16);
      const s16x8 kf1 = *(const s16x8*)(Kb + 8192 + d * 1024 + lane * 16);
      sf[0] = __builtin_amdgcn_mfma_f32_16x16x32_bf16(kf0, qf[d], sf[0], 0, 0, 0);
      sf[1] = __builtin_amdgcn_mfma_f32_16x16x32_bf16(kf1, qf[d], sf[1], 0, 0, 0);
    }
    __builtin_amdgcn_s_setprio(0);

    // lane-local online softmax, exp2 units, defer-max (THR=11 ~ e^7.6)
    float mx = sf[0][0];
#pragma unroll
    for (int nf = 0; nf < 2; nf++)
#pragma unroll
      for (int r = 0; r < 4; r++) mx = fmaxf(mx, sf[nf][r]);
    mx = fmaxf(mx, __shfl_xor(mx, 16, 64));
    mx = fmaxf(mx, __shfl_xor(mx, 32, 64));
    if (__any(mx > m_l + 11.0f)) {  // wave-uniform rescale
      const float mn = fmaxf(m_l, mx);
      const float scr = ex2(m_l - mn);
      m_l = mn;
      l_l *= scr;
      float so[4];
#pragma unroll
      for (int r = 0; r < 4; r++) so[r] = __shfl(scr, g * 4 + r, 64);
#pragma unroll
      for (int f = 0; f < 16; f++)
#pragma unroll
        for (int r = 0; r < 4; r++) o[f][r] *= so[r];
    }
    float sum = 0.f;
#pragma unroll
    for (int nf = 0; nf < 2; nf++)
#pragma unroll
      for (int r = 0; r < 4; r++) {
        const float p = ex2(sf[nf][r] - m_l);
        sf[nf][r] = p;
        sum += p;
      }
    sum += __shfl_xor(sum, 16, 64);
    sum += __shfl_xor(sum, 32, 64);
    l_l += sum;

    // P -> wave-private LDS packed bf16x2, 2 x ds_write_b64 (8B aligned)
#pragma unroll
    for (int nf = 0; nf < 2; nf++) {
      const int base = c * 40 + nf * 16 + g * 4;
      const u64 lo = (u64)pack2bf(sf[nf][0], sf[nf][1]);
      const u64 hi = (u64)pack2bf(sf[nf][2], sf[nf][3]);
      *(u64*)&Ps[base] = lo | (hi << 32);
    }

    // O += P V (PV B-operand read sequential from fragment-major V image)
    const s16x8 pa = *(const s16x8*)&Ps[c * 40 + g * 8];
    __builtin_amdgcn_s_setprio(1);
#pragma unroll
    for (int f = 0; f < 16; ++f) {
      const s16x8 vf = *(const s16x8*)(Vb + f * 1024 + lane * 16);
      o[f] = __builtin_amdgcn_mfma_f32_16x16x32_bf16(pa, vf, o[f], 0, 0, 0);
    }
    __builtin_amdgcn_s_setprio(0);

    __syncthreads();  // drains stage(t+1) DMA + this tile's LDS reads
  }

  // ---- merge the two kv-half states and write out ----
  float(*Om)[260] = (float(*)[260])smem;        // 66560 B (stage region dead)
  float(*Ml)[2] = (float(*)[2])(smem + 66560);  // 512 B
  float m0r[4], l0r[4];
#pragma unroll
  for (int r = 0; r < 4; r++) {
    m0r[r] = __shfl(m_l, g * 4 + r, 64);
    l0r[r] = __shfl(l_l, g * 4 + r, 64);
  }
  if (grp == 1) {
#pragma unroll
    for (int f = 0; f < 16; f++)
#pragma unroll
      for (int r = 0; r < 4; r++)
        Om[wq * 16 + g * 4 + r][f * 16 + c] = o[f][r];
    if (g == 0) {
      Ml[wq * 16 + c][0] = m_l;
      Ml[wq * 16 + c][1] = l_l;
    }
  }
  __syncthreads();
  if (grp == 0) {
    float e0v[4], e1v[4], inv[4];
#pragma unroll
    for (int r = 0; r < 4; r++) {
      const int rw = wq * 16 + g * 4 + r;
      const float m1 = Ml[rw][0], l1 = Ml[rw][1];
      const float ms = fmaxf(m0r[r], m1);
      e0v[r] = ex2(m0r[r] - ms);
      e1v[r] = ex2(m1 - ms);
      inv[r] = 1.0f / (l0r[r] * e0v[r] + l1 * e1v[r]);
    }
#pragma unroll
    for (int f = 0; f < 16; f++) {
#pragma unroll
      for (int r = 0; r < 4; r++) {
        const int rw = wq * 16 + g * 4 + r;
        out[((b << 11) + q0 + rw) * 256 + f * 16 + c] =
            (o[f][r] * e0v[r] + Om[rw][f * 16 + c] * e1v[r]) * inv[r];
      }
    }
  }
}

extern "C" void kernel_launch(void* const* d_in, const int* in_sizes, int n_in,
                              void* d_out, int out_size, void* d_ws,
                              size_t ws_size, hipStream_t stream) {
  const float* q_in = (const float*)d_in[0];
  const float* k_in = (const float*)d_in[1];
  const float* v_in = (const float*)d_in[2];
  const float* Wq = (const float*)d_in[3];
  const float* bq = (const float*)d_in[4];
  const float* Wk = (const float*)d_in[5];
  const float* bk = (const float*)d_in[6];
  const float* Wv = (const float*)d_in[7];
  const float* bv = (const float*)d_in[8];
  float* out = (float*)d_out;

  char* ws = (char*)d_ws;
  short* qsb = (short*)d_out;  // Q bf16 in first 512B of each out row
  char* ksb = ws;              // 8 MB K fragment-major tile images
  char* vtb = ws + (8 << 20);  // 8 MB V fragment-major tile images

  proj3<<<dim3(768), dim3(256), 0, stream>>>(q_in, k_in, v_in, bq, bk, bv, Wq,
                                             Wk, Wv, qsb, ksb, vtb);
  attn_fused<<<dim3(256), dim3(512), 0, stream>>>(qsb, ksb, vtb, out);
}